// Round 18
// baseline (180.391 us; speedup 1.0000x reference)
//
#include <hip/hip_runtime.h>

// MQA: B=2, S=2048, HID=2048, H=16, D=128 (single KV head), causal.
// Pipeline: cast (merged) -> fused QKV NT-GEMM (gemm4 NJ=3, 768 blocks) ->
//           V transpose -> kmax -> flash attention (split-KV, 4-wave blocks,
//           in-register P, ones-MFMA row-sums; R14/R16 proven version) ->
//           combine -> out NT-GEMM (NJ=4).

#define S_LEN 2048
#define HID_  2048
#define D_    128
#define NQKV  2304   // 2048 Q + 128 K + 128 V columns

typedef __attribute__((ext_vector_type(8))) short bf16x8;
typedef __attribute__((ext_vector_type(4))) float f32x4;
typedef __attribute__((ext_vector_type(16))) float f32x16;

__device__ __forceinline__ unsigned short f2b(float f) {
  union { float f; unsigned int u; } a; a.f = f;
  unsigned int u = a.u;
  return (unsigned short)((u + 0x7fffu + ((u >> 16) & 1u)) >> 16);  // RNE
}

__device__ __forceinline__ float b2f(unsigned short s) {
  union { unsigned int u; float f; } a; a.u = ((unsigned int)s) << 16;
  return a.f;
}

__device__ __forceinline__ void load_lds16(const void* g, void* l) {
  __builtin_amdgcn_global_load_lds(
      (const __attribute__((address_space(1))) void*)g,
      (__attribute__((address_space(3))) void*)l, 16, 0, 0);
}

__device__ __forceinline__ f32x4 mfma16(bf16x8 a, bf16x8 b, f32x4 c) {
  return __builtin_amdgcn_mfma_f32_16x16x32_bf16(a, b, c, 0, 0, 0);
}

__device__ __forceinline__ f32x16 mfma32(bf16x8 a, bf16x8 b, f32x16 c) {
  return __builtin_amdgcn_mfma_f32_32x32x16_bf16(a, b, c, 0, 0, 0);
}

__device__ __forceinline__ unsigned int cvtpk(float lo, float hi) {
  unsigned int r;
  asm volatile("v_cvt_pk_bf16_f32 %0, %1, %2" : "=v"(r) : "v"(lo), "v"(hi));
  return r;
}

// ---------------- casts / packing ----------------

__global__ void cast2_f32_bf16_k(const float* __restrict__ x,
                                 unsigned short* __restrict__ xb,
                                 const float* __restrict__ Wo,
                                 unsigned short* __restrict__ Wob,
                                 int nx4, int nw4) {
  const int idx = blockIdx.x * 256 + threadIdx.x;
  const float4* src;
  ushort4* dst;
  if (idx < nx4) { src = (const float4*)x + idx; dst = (ushort4*)xb + idx; }
  else {
    const int j = idx - nx4;
    if (j >= nw4) return;
    src = (const float4*)Wo + j; dst = (ushort4*)Wob + j;
  }
  const float4 v = *src;
  ushort4 o;
  o.x = f2b(v.x); o.y = f2b(v.y); o.z = f2b(v.z); o.w = f2b(v.w);
  *dst = o;
}

__global__ void build_wcat_k(const float* __restrict__ Wq,
                             const float* __restrict__ Wk,
                             const float* __restrict__ Wv,
                             const float* __restrict__ bq,
                             const float* __restrict__ bk,
                             const float* __restrict__ bv,
                             unsigned short* __restrict__ Wcat,
                             float* __restrict__ bcat,
                             float* __restrict__ Kmax) {
  const int idx = blockIdx.x * 256 + threadIdx.x;
  const int i = idx * 4;
  const int row = i >> 11;
  const int col = i & 2047;
  const float* src;
  if (row < 2048)      src = Wq + (size_t)row * 2048 + col;
  else if (row < 2176) src = Wk + (size_t)(row - 2048) * 2048 + col;
  else                 src = Wv + (size_t)(row - 2176) * 2048 + col;
  const float4 v = *(const float4*)src;
  ushort4 o;
  o.x = f2b(v.x); o.y = f2b(v.y); o.z = f2b(v.z); o.w = f2b(v.w);
  *(ushort4*)(Wcat + i) = o;
  if (idx < NQKV)
    bcat[idx] = (idx < 2048) ? bq[idx] : (idx < 2176) ? bk[idx - 2048] : bv[idx - 2176];
  if (idx < 2) Kmax[idx] = 0.f;   // re-init every launch (runs before kmax_k)
}

// Vt[b][d][s] = QKV[b*S+s][2176+d] -- LDS-tiled transpose
__global__ __launch_bounds__(256)
void transpose_v(const unsigned short* __restrict__ QKV,
                 unsigned short* __restrict__ Vt) {
  __shared__ unsigned short tile[64][136];
  const int tid = threadIdx.x;
  const int s0  = blockIdx.x * 64;
  const int b   = blockIdx.y;
  const int row = tid >> 2;
  const int cb  = (tid & 3) * 32;
  const unsigned short* src = QKV + (size_t)(b * S_LEN + s0 + row) * NQKV + 2176 + cb;
#pragma unroll
  for (int i = 0; i < 4; ++i)
    *(bf16x8*)&tile[row][cb + i * 8] = *(const bf16x8*)(src + i * 8);
  __syncthreads();
  const int d  = tid >> 1;
  const int sc = (tid & 1) * 32;
  unsigned short* dst = Vt + ((size_t)b * D_ + d) * S_LEN + s0 + sc;
#pragma unroll
  for (int i = 0; i < 4; ++i) {
    bf16x8 vv;
#pragma unroll
    for (int e = 0; e < 8; ++e) vv[e] = tile[sc + i * 8 + e][d];
    *(bf16x8*)(dst + i * 8) = vv;
  }
}

// max_s ||k[b,s]||^2 -> Kmax[b] (as float bits via atomicMax on uint)
__global__ __launch_bounds__(256)
void kmax_k(const unsigned short* __restrict__ QKV, float* __restrict__ Kmax) {
  __shared__ float red[256];
  const int tid = threadIdx.x;
  const int b = blockIdx.x >> 3;
  const int s = (blockIdx.x & 7) * 256 + tid;
  const unsigned short* kp = QKV + (size_t)(b * S_LEN + s) * NQKV + 2048;
  float sum = 0.f;
#pragma unroll
  for (int i = 0; i < 16; ++i) {
    bf16x8 v = *(const bf16x8*)(kp + i * 8);
#pragma unroll
    for (int e = 0; e < 8; ++e) { const float f = b2f((unsigned short)v[e]); sum += f * f; }
  }
  red[tid] = sum;
  __syncthreads();
  for (int off = 128; off > 0; off >>= 1) {
    if (tid < off) red[tid] = fmaxf(red[tid], red[tid + off]);
    __syncthreads();
  }
  if (tid == 0) atomicMax((unsigned int*)(Kmax + b), __float_as_uint(red[0]));
}

// ---------------- NT GEMM: m97 geometry + counted-vmcnt 3-buf ----------------

template <int OUT_F32, int NJ>
__global__ __launch_bounds__(256, 3)
void gemm4(const unsigned short* __restrict__ A,
           const unsigned short* __restrict__ Bm,
           const float* __restrict__ bias,
           void* __restrict__ Cv,
           int N, int K) {
  constexpr int BN = 32 * NJ;
  __shared__ __align__(16) char As[3][128 * 64];
  __shared__ __align__(16) char Bs[3][BN * 64];

  const int tid  = threadIdx.x;
  const int lane = tid & 63;
  const int wv   = tid >> 6;       // 0..3
  const int wr   = wv >> 1, wc = wv & 1;
  const int g    = lane >> 4, r = lane & 15;

  const int nwg  = gridDim.x;
  const int bid  = blockIdx.x;
  const int sbid = (bid & 7) * (nwg >> 3) + (bid >> 3);   // XCD-chunked
  const int nx   = N / BN;
  const int m0   = (sbid / nx) * 128;
  const int n0   = (sbid % nx) * BN;
  const int NT   = K >> 5;

  const size_t Kb = (size_t)K * 2;
  const char* Ab = (const char*)A + (size_t)m0 * Kb;
  const char* Bb = (const char*)Bm + (size_t)n0 * Kb;

#define STG(bufi, t)                                                           \
  {                                                                            \
    const int kb_ = (t) * 64;                                                  \
    _Pragma("unroll")                                                          \
    for (int i_ = 0; i_ < 2; ++i_) {                                           \
      const int ch_ = tid + 256 * i_;                                          \
      const int rr_ = ch_ >> 2;                                                \
      const int sl_ = (ch_ & 3) ^ (rr_ & 3);                                   \
      load_lds16(Ab + (size_t)rr_ * Kb + kb_ + sl_ * 16, As[bufi] + ch_ * 16); \
      if (NJ == 4 || ch_ < 128 * NJ)                                           \
        load_lds16(Bb + (size_t)rr_ * Kb + kb_ + sl_ * 16, Bs[bufi] + ch_ * 16); \
    }                                                                          \
  }
#define WAIT_TILE()                                                            \
  {                                                                            \
    if (NJ == 4 || tid < 128) { asm volatile("s_waitcnt vmcnt(4)" ::: "memory"); } \
    else                      { asm volatile("s_waitcnt vmcnt(3)" ::: "memory"); } \
  }

  f32x4 acc[4][NJ] = {};
  const int ss = ((g ^ (r & 3)) << 4);   // slot byte for this lane's k-group

  STG(0, 0) STG(1, 1)
  WAIT_TILE()                             // buf0 ready, buf1 in flight (R8 fix)
  __builtin_amdgcn_s_barrier();
  __builtin_amdgcn_sched_barrier(0);

  for (int t = 0; t < NT; ++t) {
    const char* as = (const char*)As[t % 3];
    const char* bs = (const char*)Bs[t % 3];
    const bool pf = (t + 2 < NT);

    bf16x8 af[4], bfr[NJ];
#pragma unroll
    for (int i = 0; i < 4; ++i)
      af[i] = *(const bf16x8*)(as + (wr * 64 + i * 16 + r) * 64 + ss);
#pragma unroll
    for (int j = 0; j < NJ; ++j)
      bfr[j] = *(const bf16x8*)(bs + (wc * 16 * NJ + j * 16 + r) * 64 + ss);
    if (pf) STG((t + 2) % 3, t + 2)

    asm volatile("s_waitcnt lgkmcnt(0)" ::: "memory");
    __builtin_amdgcn_sched_barrier(0);            // rule 18
    __builtin_amdgcn_s_setprio(1);
#pragma unroll
    for (int i = 0; i < 4; ++i)
#pragma unroll
      for (int j = 0; j < NJ; ++j)
        acc[i][j] = mfma16(af[i], bfr[j], acc[i][j]);
    __builtin_amdgcn_s_setprio(0);

    if (t + 1 < NT) {
      if (pf) { WAIT_TILE() }
      else    { asm volatile("s_waitcnt vmcnt(0)" ::: "memory"); }
      __builtin_amdgcn_s_barrier();
      __builtin_amdgcn_sched_barrier(0);
    }
  }

#pragma unroll
  for (int i = 0; i < 4; ++i) {
    const int row = m0 + wr * 64 + i * 16 + g * 4;
#pragma unroll
    for (int j = 0; j < NJ; ++j) {
      const int col = n0 + wc * 16 * NJ + j * 16 + r;
      const float bb = bias[col];
#pragma unroll
      for (int e = 0; e < 4; ++e) {
        const float v = acc[i][j][e] + bb;
        if (OUT_F32) ((float*)Cv)[(size_t)(row + e) * N + col] = v;
        else ((unsigned short*)Cv)[(size_t)(row + e) * N + col] = f2b(v);
      }
    }
  }
#undef STG
#undef WAIT_TILE
}

// ---------------- flash attention (causal, MQA, split-KV) ----------------
// R14/R16 proven version: 4-wave blocks, KVBLK=64 dbuf, fixed-m0 Cauchy
// softmax => additive split-KV partials; ones-MFMA row-sums.
// R15 lesson: 8-wave variants spill (needs 2-waves/SIMD reg budget).
// R17 lesson: 16x16 bpermute-redistribution variant NaN'd — do not retry
// without a refcheck harness.

__global__ __launch_bounds__(256, 2)
void mqa_attn(const unsigned short* __restrict__ QKV,
              const unsigned short* __restrict__ Vt,
              const float* __restrict__ Kmax,
              unsigned short* __restrict__ Ob,
              unsigned short* __restrict__ Pacc,
              float* __restrict__ Pl) {
  __shared__ __align__(16) char Ks[2][64 * 256];
  __shared__ __align__(16) char Vs[2][64 * 256];

  const int tid  = threadIdx.x;
  const int lane = tid & 63;
  const int wv   = tid >> 6;           // 0..3 (head within block)
  const int ln   = lane & 31;
  const int hi   = lane >> 5;
  const int x    = blockIdx.x;         // 0..767
  const int bhq  = x & 7;
  const int b    = bhq >> 2;
  const int hq   = bhq & 3;
  const int widx = x >> 3;             // 0..95, largest work first
  int qt, t0, te, chunk;
  if (widx < 32)      { qt = 32 + widx; t0 = 0;  te = 16;         chunk = 0; }
  else if (widx < 64) { qt = 95 - widx; t0 = 16; te = qt / 2 + 1; chunk = 1; }
  else                { qt = 95 - widx; t0 = 0;  te = qt / 2 + 1; chunk = -1; }
  const int h    = hq * 4 + wv;
  const int qw   = qt * 32;
  const int lastT = qt / 2;            // index of the diagonal tile

  bf16x8 qf[8];
  {
    const unsigned short* qp =
        QKV + (size_t)(b * S_LEN + qw + ln) * NQKV + h * D_ + hi * 8;
#pragma unroll
    for (int ch = 0; ch < 8; ++ch) qf[ch] = *(const bf16x8*)(qp + ch * 16);
  }

  const float sscale = 0.08838834764831845f * 1.4426950408889634f;  // scale*log2e
  float qn2 = 0.f;
#pragma unroll
  for (int ch = 0; ch < 8; ++ch)
#pragma unroll
    for (int e = 0; e < 8; ++e) {
      const float qv = b2f((unsigned short)qf[ch][e]);
      qn2 += qv * qv;
    }
  qn2 += __shfl_xor(qn2, 32);
  const float m0c = sqrtf(qn2) * sqrtf(Kmax[b]) * sscale + 1.0f;

  const char* kbc = (const char*)(QKV + (size_t)(b * S_LEN) * NQKV + 2048);
  const char* vbc = (const char*)(Vt + (size_t)b * D_ * S_LEN);

  f32x16 acc[4] = {};
  f32x16 accl = {};                    // row sums, same D-layout as acc
  bf16x8 onesf;
#pragma unroll
  for (int e = 0; e < 8; ++e) onesf[e] = (short)0x3F80;  // bf16 1.0

#define STAGE(bufi, t)                                                         \
  {                                                                            \
    const int kv0_ = (t) * 64;                                                 \
    _Pragma("unroll")                                                          \
    for (int i_ = 0; i_ < 4; ++i_) {                                           \
      const int ch_ = tid + 256 * i_;                                          \
      const int kr_ = ch_ >> 4;                                                \
      const int kg_ = (ch_ & 15) ^ (kr_ & 15);                                 \
      load_lds16(kbc + (size_t)(kv0_ + kr_) * (NQKV * 2) + kg_ * 16,           \
                 Ks[bufi] + ch_ * 16);                                         \
      const int vg_ = (ch_ & 15) ^ (kr_ & 15);                                 \
      const int vd_ = kr_ * 2 + (vg_ >> 3);                                    \
      load_lds16(vbc + (size_t)vd_ * (S_LEN * 2) + kv0_ * 2 + (vg_ & 7) * 16,  \
                 Vs[bufi] + ch_ * 16);                                         \
    }                                                                          \
  }

  STAGE(0, t0);
  int cur = 0;

  for (int t = t0; t < te; ++t) {
    __syncthreads();
    if (t + 1 < te) STAGE(cur ^ 1, t + 1);

    const char* ksb = Ks[cur];
    const char* vsb = Vs[cur];
    const int kv0 = t * 64;
    const bool last = (t == lastT);
    const bool doUp = (kv0 + 32 <= qw + 31);
    cur ^= 1;

    f32x16 sA = {}, sB = {};
    __builtin_amdgcn_s_setprio(1);
#pragma unroll
    for (int ch = 0; ch < 8; ++ch) {
      const int slot0 = (2 * ch + hi) ^ (ln & 15);
      const bf16x8 kf0 = *(const bf16x8*)(ksb + ln * 256 + slot0 * 16);
      sA = mfma32(kf0, qf[ch], sA);
      if (doUp) {
        const bf16x8 kf1 = *(const bf16x8*)(ksb + (32 + ln) * 256 + slot0 * 16);
        sB = mfma32(kf1, qf[ch], sB);
      }
    }
    __builtin_amdgcn_s_setprio(0);

    bf16x8 pa0, pa1, pa2, pa3;
    float p[16];

#define SOFTMAX(sv, kvtbase)                                                   \
    _Pragma("unroll")                                                          \
    for (int rr = 0; rr < 16; ++rr) {                                          \
      float e = sv[rr] * sscale - m0c;                                         \
      if (last) {                                                              \
        const int kva = (kvtbase) + (rr & 3) + 8 * (rr >> 2) + 4 * hi;         \
        e = (kva <= qw + ln) ? e : -__builtin_inff();                          \
      }                                                                        \
      p[rr] = __builtin_amdgcn_exp2f(e);                                       \
    }

#define PACK2(fa, fb)                                                          \
    {                                                                          \
      const unsigned int A0 = cvtpk(p[0], p[1]),   A1 = cvtpk(p[2], p[3]);     \
      const unsigned int B0 = cvtpk(p[4], p[5]),   B1 = cvtpk(p[6], p[7]);     \
      const unsigned int C0 = cvtpk(p[8], p[9]),   C1 = cvtpk(p[10], p[11]);   \
      const unsigned int D0 = cvtpk(p[12], p[13]), D1 = cvtpk(p[14], p[15]);   \
      unsigned int X0 = hi ? A0 : B0, X1 = hi ? A1 : B1;                       \
      unsigned int Y0 = hi ? C0 : D0, Y1 = hi ? C1 : D1;                       \
      X0 = (unsigned int)__shfl_xor((int)X0, 32);                              \
      X1 = (unsigned int)__shfl_xor((int)X1, 32);                              \
      Y0 = (unsigned int)__shfl_xor((int)Y0, 32);                              \
      Y1 = (unsigned int)__shfl_xor((int)Y1, 32);                              \
      union { unsigned int w[4]; bf16x8 v; } ua, ub;                           \
      ua.w[0] = hi ? X0 : A0; ua.w[1] = hi ? X1 : A1;                          \
      ua.w[2] = hi ? B0 : X0; ua.w[3] = hi ? B1 : X1;                          \
      ub.w[0] = hi ? Y0 : C0; ub.w[1] = hi ? Y1 : C1;                          \
      ub.w[2] = hi ? D0 : Y0; ub.w[3] = hi ? D1 : Y1;                          \
      fa = ua.v; fb = ub.v;                                                    \
    }

    SOFTMAX(sA, kv0)
    PACK2(pa0, pa1)
    if (doUp) {
      SOFTMAX(sB, kv0 + 32)
      PACK2(pa2, pa3)
    }

    __builtin_amdgcn_s_setprio(1);
    accl = mfma32(pa0, onesf, accl);
    accl = mfma32(pa1, onesf, accl);
    if (doUp) {
      accl = mfma32(pa2, onesf, accl);
      accl = mfma32(pa3, onesf, accl);
    }
#pragma unroll
    for (int dt = 0; dt < 4; ++dt) {
      const int vrow = dt * 16 + (ln >> 1);
      const int gb   = (ln & 1) << 3;
      {
        const int sl = (gb + 0 + hi) ^ (vrow & 15);
        const bf16x8 vf = *(const bf16x8*)(vsb + vrow * 256 + sl * 16);
        acc[dt] = mfma32(pa0, vf, acc[dt]);
      }
      {
        const int sl = (gb + 2 + hi) ^ (vrow & 15);
        const bf16x8 vf = *(const bf16x8*)(vsb + vrow * 256 + sl * 16);
        acc[dt] = mfma32(pa1, vf, acc[dt]);
      }
      if (doUp) {
        {
          const int sl = (gb + 4 + hi) ^ (vrow & 15);
          const bf16x8 vf = *(const bf16x8*)(vsb + vrow * 256 + sl * 16);
          acc[dt] = mfma32(pa2, vf, acc[dt]);
        }
        {
          const int sl = (gb + 6 + hi) ^ (vrow & 15);
          const bf16x8 vf = *(const bf16x8*)(vsb + vrow * 256 + sl * 16);
          acc[dt] = mfma32(pa3, vf, acc[dt]);
        }
      }
    }
    __builtin_amdgcn_s_setprio(0);
#undef SOFTMAX
#undef PACK2
  }

  if (chunk < 0) {
    unsigned short* ob = Ob + (size_t)(b * S_LEN + qw) * HID_ + h * D_ + ln;
#pragma unroll
    for (int rr = 0; rr < 16; ++rr) {
      const int qr = (rr & 3) + 8 * (rr >> 2) + 4 * hi;
      const float inv = 1.0f / accl[rr];
#pragma unroll
      for (int dt = 0; dt < 4; ++dt)
        ob[(size_t)qr * HID_ + dt * 32] = f2b(acc[dt][rr] * inv);
    }
  } else {
    const int slot = ((chunk * 2 + b) * 16 + h) * 32 + (qt - 32);
    unsigned short* pa = Pacc + (size_t)slot * 32 * 128 + ln;
#pragma unroll
    for (int rr = 0; rr < 16; ++rr) {
      const int qr = (rr & 3) + 8 * (rr >> 2) + 4 * hi;
#pragma unroll
      for (int dt = 0; dt < 4; ++dt)
        pa[qr * 128 + dt * 32] = f2b(acc[dt][rr]);
    }
    if (ln == 0) {
#pragma unroll
      for (int rr = 0; rr < 16; ++rr) {
        const int qr = (rr & 3) + 8 * (rr >> 2) + 4 * hi;
        Pl[slot * 32 + qr] = accl[rr];
      }
    }
  }
#undef STAGE
}

// combine: out = (A0 + A1) / (L0 + L1) for all split (b,h,qt>=32)
__global__ __launch_bounds__(256)
void combine_k(const unsigned short* __restrict__ Pacc,
               const float* __restrict__ Pl,
               unsigned short* __restrict__ Ob) {
  const int x  = blockIdx.x;           // 1024 = b(2) x h(16) x qs(32)
  const int qs = x & 31;
  const int h  = (x >> 5) & 15;
  const int b  = x >> 9;
  const int tid = threadIdx.x;
  const int q  = tid >> 3;             // 0..31
  const int dp = (tid & 7) * 16;       // 0..112
  const int s0 = (b * 16 + h) * 32 + qs;
  const int s1 = ((2 + b) * 16 + h) * 32 + qs;
  const float inv = 1.0f / (Pl[s0 * 32 + q] + Pl[s1 * 32 + q]);
  const unsigned short* a0 = Pacc + ((size_t)s0 * 32 + q) * 128 + dp;
  const unsigned short* a1 = Pacc + ((size_t)s1 * 32 + q) * 128 + dp;
  unsigned short* ob =
      Ob + (size_t)(b * S_LEN + (32 + qs) * 32 + q) * HID_ + h * D_ + dp;
  const bf16x8 v0a = *(const bf16x8*)a0, v0b = *(const bf16x8*)(a0 + 8);
  const bf16x8 v1a = *(const bf16x8*)a1, v1b = *(const bf16x8*)(a1 + 8);
  bf16x8 oa, obv;
#pragma unroll
  for (int e = 0; e < 8; ++e) {
    oa[e]  = (short)f2b((b2f((unsigned short)v0a[e]) + b2f((unsigned short)v1a[e])) * inv);
    obv[e] = (short)f2b((b2f((unsigned short)v0b[e]) + b2f((unsigned short)v1b[e])) * inv);
  }
  *(bf16x8*)ob = oa;
  *(bf16x8*)(ob + 8) = obv;
}

// ---------------- launcher ----------------

extern "C" void kernel_launch(void* const* d_in, const int* in_sizes, int n_in,
                              void* d_out, int out_size, void* d_ws, size_t ws_size,
                              hipStream_t stream) {
  (void)in_sizes; (void)n_in; (void)out_size; (void)ws_size;
  const float* x  = (const float*)d_in[0];
  const float* Wq = (const float*)d_in[2];
  const float* bq = (const float*)d_in[3];
  const float* Wk = (const float*)d_in[4];
  const float* bk = (const float*)d_in[5];
  const float* Wv = (const float*)d_in[6];
  const float* bv = (const float*)d_in[7];
  const float* Wo = (const float*)d_in[8];
  const float* bo = (const float*)d_in[9];
  float* out = (float*)d_out;

  char* p = (char*)d_ws;
  unsigned short* xb   = (unsigned short*)p;  p += (size_t)4096 * 2048 * 2;
  unsigned short* Wcat = (unsigned short*)p;  p += (size_t)2304 * 2048 * 2;
  float*          bcat = (float*)p;           p += 16384;
  unsigned short* Wob  = (unsigned short*)p;  p += (size_t)2048 * 2048 * 2;
  unsigned short* QKV  = (unsigned short*)p;  p += (size_t)4096 * 2304 * 2;
  unsigned short* Vt   = (unsigned short*)p;  p += (size_t)2 * 128 * 2048 * 2;
  float*          Kmax = (float*)p;           p += 64;
  unsigned short* Pacc = (unsigned short*)p;  p += (size_t)2048 * 32 * 128 * 2; // 16.8MB
  float*          Pl   = (float*)p;           p += (size_t)2048 * 32 * 4;       // 256KB
  unsigned short* Ob   = xb;  // xb dead after gemm1

  cast2_f32_bf16_k<<<12288, 256, 0, stream>>>(x, xb, Wo, Wob, 2097152, 1048576);
  build_wcat_k<<<4608, 256, 0, stream>>>(Wq, Wk, Wv, bq, bk, bv, Wcat, bcat, Kmax);
  gemm4<0, 3><<<768, 256, 0, stream>>>(xb, Wcat, bcat, QKV, 2304, 2048);
  transpose_v<<<dim3(32, 2), 256, 0, stream>>>(QKV, Vt);
  kmax_k<<<16, 256, 0, stream>>>(QKV, Kmax);
  mqa_attn<<<768, 256, 0, stream>>>(QKV, Vt, Kmax, Ob, Pacc, Pl);
  combine_k<<<1024, 256, 0, stream>>>(Pacc, Pl, Ob);
  gemm4<1, 4><<<512, 256, 0, stream>>>(Ob, Wob, bo, out, 2048, 2048);
}

// Round 19
// 175.023 us; speedup vs baseline: 1.0307x; 1.0307x over previous
//
#include <hip/hip_runtime.h>

// MQA: B=2, S=2048, HID=2048, H=16, D=128 (single KV head), causal.
// Pipeline: prep (cast+wcat fused) -> fused QKV NT-GEMM (gemm4 NJ=3) ->
//           tvkm (V transpose + kmax fused) -> flash attention (split-KV,
//           4-wave blocks, in-register P, ones-MFMA row-sums) -> combine ->
//           out NT-GEMM (NJ=4).

#define S_LEN 2048
#define HID_  2048
#define D_    128
#define NQKV  2304   // 2048 Q + 128 K + 128 V columns

typedef __attribute__((ext_vector_type(8))) short bf16x8;
typedef __attribute__((ext_vector_type(4))) float f32x4;
typedef __attribute__((ext_vector_type(16))) float f32x16;

__device__ __forceinline__ unsigned short f2b(float f) {
  union { float f; unsigned int u; } a; a.f = f;
  unsigned int u = a.u;
  return (unsigned short)((u + 0x7fffu + ((u >> 16) & 1u)) >> 16);  // RNE
}

__device__ __forceinline__ float b2f(unsigned short s) {
  union { unsigned int u; float f; } a; a.u = ((unsigned int)s) << 16;
  return a.f;
}

__device__ __forceinline__ void load_lds16(const void* g, void* l) {
  __builtin_amdgcn_global_load_lds(
      (const __attribute__((address_space(1))) void*)g,
      (__attribute__((address_space(3))) void*)l, 16, 0, 0);
}

__device__ __forceinline__ f32x4 mfma16(bf16x8 a, bf16x8 b, f32x4 c) {
  return __builtin_amdgcn_mfma_f32_16x16x32_bf16(a, b, c, 0, 0, 0);
}

__device__ __forceinline__ f32x16 mfma32(bf16x8 a, bf16x8 b, f32x16 c) {
  return __builtin_amdgcn_mfma_f32_32x32x16_bf16(a, b, c, 0, 0, 0);
}

__device__ __forceinline__ unsigned int cvtpk(float lo, float hi) {
  unsigned int r;
  asm volatile("v_cvt_pk_bf16_f32 %0, %1, %2" : "=v"(r) : "v"(lo), "v"(hi));
  return r;
}

// ---------------- prep: casts + Wcat/bcat build, fused by block range -------

__global__ void prep_k(const float* __restrict__ x,
                       unsigned short* __restrict__ xb,
                       const float* __restrict__ Wo,
                       unsigned short* __restrict__ Wob,
                       const float* __restrict__ Wq,
                       const float* __restrict__ Wk,
                       const float* __restrict__ Wv,
                       const float* __restrict__ bq,
                       const float* __restrict__ bk,
                       const float* __restrict__ bv,
                       unsigned short* __restrict__ Wcat,
                       float* __restrict__ bcat,
                       float* __restrict__ Kmax) {
  const int bidx = blockIdx.x;
  const int tid  = threadIdx.x;
  if (bidx < 12288) {
    // cast x (2097152 float4) then Wo (1048576 float4) to bf16
    const int idx = bidx * 256 + tid;
    const float4* src;
    ushort4* dst;
    if (idx < 2097152) { src = (const float4*)x + idx; dst = (ushort4*)xb + idx; }
    else {
      const int j = idx - 2097152;
      src = (const float4*)Wo + j; dst = (ushort4*)Wob + j;
    }
    const float4 v = *src;
    ushort4 o;
    o.x = f2b(v.x); o.y = f2b(v.y); o.z = f2b(v.z); o.w = f2b(v.w);
    *dst = o;
  } else {
    // build Wcat/bcat (+ Kmax zero-init)
    const int idx = (bidx - 12288) * 256 + tid;
    const int i = idx * 4;
    const int row = i >> 11;
    const int col = i & 2047;
    const float* src;
    if (row < 2048)      src = Wq + (size_t)row * 2048 + col;
    else if (row < 2176) src = Wk + (size_t)(row - 2048) * 2048 + col;
    else                 src = Wv + (size_t)(row - 2176) * 2048 + col;
    const float4 v = *(const float4*)src;
    ushort4 o;
    o.x = f2b(v.x); o.y = f2b(v.y); o.z = f2b(v.z); o.w = f2b(v.w);
    *(ushort4*)(Wcat + i) = o;
    if (idx < NQKV)
      bcat[idx] = (idx < 2048) ? bq[idx] : (idx < 2176) ? bk[idx - 2048] : bv[idx - 2176];
    if (idx < 2) Kmax[idx] = 0.f;   // re-init every launch (before tvkm_k)
  }
}

// ---------------- tvkm: V transpose + K row-norm max, fused ----------------
// Vt[b][d][s] = QKV[b*S+s][2176+d];  Kmax[b] = max_s ||k[b,s]||^2.

__global__ __launch_bounds__(256)
void tvkm_k(const unsigned short* __restrict__ QKV,
            unsigned short* __restrict__ Vt,
            float* __restrict__ Kmax) {
  __shared__ unsigned short tile[64][136];
  __shared__ float red[64];
  const int tid = threadIdx.x;
  const int s0  = blockIdx.x * 64;
  const int b   = blockIdx.y;
  const int row = tid >> 2;
  const int q4  = tid & 3;
  const int cb  = q4 * 32;
  const unsigned short* rowp = QKV + (size_t)(b * S_LEN + s0 + row) * NQKV;
  // V -> LDS tile
  const unsigned short* srcV = rowp + 2176 + cb;
#pragma unroll
  for (int i = 0; i < 4; ++i)
    *(bf16x8*)&tile[row][cb + i * 8] = *(const bf16x8*)(srcV + i * 8);
  // K row norm (threads q4<2 split the 128 elements)
  float sum = 0.f;
  if (q4 < 2) {
    const unsigned short* kp = rowp + 2048 + q4 * 64;
#pragma unroll
    for (int i = 0; i < 8; ++i) {
      bf16x8 v = *(const bf16x8*)(kp + i * 8);
#pragma unroll
      for (int e = 0; e < 8; ++e) { const float f = b2f((unsigned short)v[e]); sum += f * f; }
    }
  }
  sum += __shfl_xor(sum, 1);            // pair (4r, 4r+1)
  if (q4 == 0) red[row] = sum;
  __syncthreads();
  if (tid < 64) {                       // wave 0: butterfly max over 64 rows
    float m = red[tid];
    m = fmaxf(m, __shfl_xor(m, 1));
    m = fmaxf(m, __shfl_xor(m, 2));
    m = fmaxf(m, __shfl_xor(m, 4));
    m = fmaxf(m, __shfl_xor(m, 8));
    m = fmaxf(m, __shfl_xor(m, 16));
    m = fmaxf(m, __shfl_xor(m, 32));
    if (tid == 0) atomicMax((unsigned int*)(Kmax + b), __float_as_uint(m));
  }
  // V transpose store
  const int d  = tid >> 1;
  const int sc = (tid & 1) * 32;
  unsigned short* dst = Vt + ((size_t)b * D_ + d) * S_LEN + s0 + sc;
#pragma unroll
  for (int i = 0; i < 4; ++i) {
    bf16x8 vv;
#pragma unroll
    for (int e = 0; e < 8; ++e) vv[e] = tile[sc + i * 8 + e][d];
    *(bf16x8*)(dst + i * 8) = vv;
  }
}

// ---------------- NT GEMM: m97 geometry + counted-vmcnt 3-buf ----------------

template <int OUT_F32, int NJ>
__global__ __launch_bounds__(256, 3)
void gemm4(const unsigned short* __restrict__ A,
           const unsigned short* __restrict__ Bm,
           const float* __restrict__ bias,
           void* __restrict__ Cv,
           int N, int K) {
  constexpr int BN = 32 * NJ;
  __shared__ __align__(16) char As[3][128 * 64];
  __shared__ __align__(16) char Bs[3][BN * 64];

  const int tid  = threadIdx.x;
  const int lane = tid & 63;
  const int wv   = tid >> 6;       // 0..3
  const int wr   = wv >> 1, wc = wv & 1;
  const int g    = lane >> 4, r = lane & 15;

  const int nwg  = gridDim.x;
  const int bid  = blockIdx.x;
  const int sbid = (bid & 7) * (nwg >> 3) + (bid >> 3);   // XCD-chunked
  const int nx   = N / BN;
  const int m0   = (sbid / nx) * 128;
  const int n0   = (sbid % nx) * BN;
  const int NT   = K >> 5;

  const size_t Kb = (size_t)K * 2;
  const char* Ab = (const char*)A + (size_t)m0 * Kb;
  const char* Bb = (const char*)Bm + (size_t)n0 * Kb;

#define STG(bufi, t)                                                           \
  {                                                                            \
    const int kb_ = (t) * 64;                                                  \
    _Pragma("unroll")                                                          \
    for (int i_ = 0; i_ < 2; ++i_) {                                           \
      const int ch_ = tid + 256 * i_;                                          \
      const int rr_ = ch_ >> 2;                                                \
      const int sl_ = (ch_ & 3) ^ (rr_ & 3);                                   \
      load_lds16(Ab + (size_t)rr_ * Kb + kb_ + sl_ * 16, As[bufi] + ch_ * 16); \
      if (NJ == 4 || ch_ < 128 * NJ)                                           \
        load_lds16(Bb + (size_t)rr_ * Kb + kb_ + sl_ * 16, Bs[bufi] + ch_ * 16); \
    }                                                                          \
  }
#define WAIT_TILE()                                                            \
  {                                                                            \
    if (NJ == 4 || tid < 128) { asm volatile("s_waitcnt vmcnt(4)" ::: "memory"); } \
    else                      { asm volatile("s_waitcnt vmcnt(3)" ::: "memory"); } \
  }

  f32x4 acc[4][NJ] = {};
  const int ss = ((g ^ (r & 3)) << 4);   // slot byte for this lane's k-group

  STG(0, 0) STG(1, 1)
  WAIT_TILE()                             // buf0 ready, buf1 in flight (R8 fix)
  __builtin_amdgcn_s_barrier();
  __builtin_amdgcn_sched_barrier(0);

  for (int t = 0; t < NT; ++t) {
    const char* as = (const char*)As[t % 3];
    const char* bs = (const char*)Bs[t % 3];
    const bool pf = (t + 2 < NT);

    bf16x8 af[4], bfr[NJ];
#pragma unroll
    for (int i = 0; i < 4; ++i)
      af[i] = *(const bf16x8*)(as + (wr * 64 + i * 16 + r) * 64 + ss);
#pragma unroll
    for (int j = 0; j < NJ; ++j)
      bfr[j] = *(const bf16x8*)(bs + (wc * 16 * NJ + j * 16 + r) * 64 + ss);
    if (pf) STG((t + 2) % 3, t + 2)

    asm volatile("s_waitcnt lgkmcnt(0)" ::: "memory");
    __builtin_amdgcn_sched_barrier(0);            // rule 18
    __builtin_amdgcn_s_setprio(1);
#pragma unroll
    for (int i = 0; i < 4; ++i)
#pragma unroll
      for (int j = 0; j < NJ; ++j)
        acc[i][j] = mfma16(af[i], bfr[j], acc[i][j]);
    __builtin_amdgcn_s_setprio(0);

    if (t + 1 < NT) {
      if (pf) { WAIT_TILE() }
      else    { asm volatile("s_waitcnt vmcnt(0)" ::: "memory"); }
      __builtin_amdgcn_s_barrier();
      __builtin_amdgcn_sched_barrier(0);
    }
  }

#pragma unroll
  for (int i = 0; i < 4; ++i) {
    const int row = m0 + wr * 64 + i * 16 + g * 4;
#pragma unroll
    for (int j = 0; j < NJ; ++j) {
      const int col = n0 + wc * 16 * NJ + j * 16 + r;
      const float bb = bias[col];
#pragma unroll
      for (int e = 0; e < 4; ++e) {
        const float v = acc[i][j][e] + bb;
        if (OUT_F32) ((float*)Cv)[(size_t)(row + e) * N + col] = v;
        else ((unsigned short*)Cv)[(size_t)(row + e) * N + col] = f2b(v);
      }
    }
  }
#undef STG
#undef WAIT_TILE
}

// ---------------- flash attention (causal, MQA, split-KV) ----------------
// R14/R16 proven version: 4-wave blocks, KVBLK=64 dbuf, fixed-m0 Cauchy
// softmax => additive split-KV partials; ones-MFMA row-sums.
// R15 lesson: 8-wave variants spill (needs 2-waves/SIMD reg budget).
// R17 lesson: 16x16 bpermute-redistribution variant NaN'd.

__global__ __launch_bounds__(256, 2)
void mqa_attn(const unsigned short* __restrict__ QKV,
              const unsigned short* __restrict__ Vt,
              const float* __restrict__ Kmax,
              unsigned short* __restrict__ Ob,
              unsigned short* __restrict__ Pacc,
              float* __restrict__ Pl) {
  __shared__ __align__(16) char Ks[2][64 * 256];
  __shared__ __align__(16) char Vs[2][64 * 256];

  const int tid  = threadIdx.x;
  const int lane = tid & 63;
  const int wv   = tid >> 6;           // 0..3 (head within block)
  const int ln   = lane & 31;
  const int hi   = lane >> 5;
  const int x    = blockIdx.x;         // 0..767
  const int bhq  = x & 7;
  const int b    = bhq >> 2;
  const int hq   = bhq & 3;
  const int widx = x >> 3;             // 0..95, largest work first
  int qt, t0, te, chunk;
  if (widx < 32)      { qt = 32 + widx; t0 = 0;  te = 16;         chunk = 0; }
  else if (widx < 64) { qt = 95 - widx; t0 = 16; te = qt / 2 + 1; chunk = 1; }
  else                { qt = 95 - widx; t0 = 0;  te = qt / 2 + 1; chunk = -1; }
  const int h    = hq * 4 + wv;
  const int qw   = qt * 32;
  const int lastT = qt / 2;            // index of the diagonal tile

  bf16x8 qf[8];
  {
    const unsigned short* qp =
        QKV + (size_t)(b * S_LEN + qw + ln) * NQKV + h * D_ + hi * 8;
#pragma unroll
    for (int ch = 0; ch < 8; ++ch) qf[ch] = *(const bf16x8*)(qp + ch * 16);
  }

  const float sscale = 0.08838834764831845f * 1.4426950408889634f;  // scale*log2e
  float qn2 = 0.f;
#pragma unroll
  for (int ch = 0; ch < 8; ++ch)
#pragma unroll
    for (int e = 0; e < 8; ++e) {
      const float qv = b2f((unsigned short)qf[ch][e]);
      qn2 += qv * qv;
    }
  qn2 += __shfl_xor(qn2, 32);
  const float m0c = sqrtf(qn2) * sqrtf(Kmax[b]) * sscale + 1.0f;

  const char* kbc = (const char*)(QKV + (size_t)(b * S_LEN) * NQKV + 2048);
  const char* vbc = (const char*)(Vt + (size_t)b * D_ * S_LEN);

  f32x16 acc[4] = {};
  f32x16 accl = {};                    // row sums, same D-layout as acc
  bf16x8 onesf;
#pragma unroll
  for (int e = 0; e < 8; ++e) onesf[e] = (short)0x3F80;  // bf16 1.0

#define STAGE(bufi, t)                                                         \
  {                                                                            \
    const int kv0_ = (t) * 64;                                                 \
    _Pragma("unroll")                                                          \
    for (int i_ = 0; i_ < 4; ++i_) {                                           \
      const int ch_ = tid + 256 * i_;                                          \
      const int kr_ = ch_ >> 4;                                                \
      const int kg_ = (ch_ & 15) ^ (kr_ & 15);                                 \
      load_lds16(kbc + (size_t)(kv0_ + kr_) * (NQKV * 2) + kg_ * 16,           \
                 Ks[bufi] + ch_ * 16);                                         \
      const int vg_ = (ch_ & 15) ^ (kr_ & 15);                                 \
      const int vd_ = kr_ * 2 + (vg_ >> 3);                                    \
      load_lds16(vbc + (size_t)vd_ * (S_LEN * 2) + kv0_ * 2 + (vg_ & 7) * 16,  \
                 Vs[bufi] + ch_ * 16);                                         \
    }                                                                          \
  }

  STAGE(0, t0);
  int cur = 0;

  for (int t = t0; t < te; ++t) {
    __syncthreads();
    if (t + 1 < te) STAGE(cur ^ 1, t + 1);

    const char* ksb = Ks[cur];
    const char* vsb = Vs[cur];
    const int kv0 = t * 64;
    const bool last = (t == lastT);
    const bool doUp = (kv0 + 32 <= qw + 31);
    cur ^= 1;

    f32x16 sA = {}, sB = {};
    __builtin_amdgcn_s_setprio(1);
#pragma unroll
    for (int ch = 0; ch < 8; ++ch) {
      const int slot0 = (2 * ch + hi) ^ (ln & 15);
      const bf16x8 kf0 = *(const bf16x8*)(ksb + ln * 256 + slot0 * 16);
      sA = mfma32(kf0, qf[ch], sA);
      if (doUp) {
        const bf16x8 kf1 = *(const bf16x8*)(ksb + (32 + ln) * 256 + slot0 * 16);
        sB = mfma32(kf1, qf[ch], sB);
      }
    }
    __builtin_amdgcn_s_setprio(0);

    bf16x8 pa0, pa1, pa2, pa3;
    float p[16];

#define SOFTMAX(sv, kvtbase)                                                   \
    _Pragma("unroll")                                                          \
    for (int rr = 0; rr < 16; ++rr) {                                          \
      float e = sv[rr] * sscale - m0c;                                         \
      if (last) {                                                              \
        const int kva = (kvtbase) + (rr & 3) + 8 * (rr >> 2) + 4 * hi;         \
        e = (kva <= qw + ln) ? e : -__builtin_inff();                          \
      }                                                                        \
      p[rr] = __builtin_amdgcn_exp2f(e);                                       \
    }

#define PACK2(fa, fb)                                                          \
    {                                                                          \
      const unsigned int A0 = cvtpk(p[0], p[1]),   A1 = cvtpk(p[2], p[3]);     \
      const unsigned int B0 = cvtpk(p[4], p[5]),   B1 = cvtpk(p[6], p[7]);     \
      const unsigned int C0 = cvtpk(p[8], p[9]),   C1 = cvtpk(p[10], p[11]);   \
      const unsigned int D0 = cvtpk(p[12], p[13]), D1 = cvtpk(p[14], p[15]);   \
      unsigned int X0 = hi ? A0 : B0, X1 = hi ? A1 : B1;                       \
      unsigned int Y0 = hi ? C0 : D0, Y1 = hi ? C1 : D1;                       \
      X0 = (unsigned int)__shfl_xor((int)X0, 32);                              \
      X1 = (unsigned int)__shfl_xor((int)X1, 32);                              \
      Y0 = (unsigned int)__shfl_xor((int)Y0, 32);                              \
      Y1 = (unsigned int)__shfl_xor((int)Y1, 32);                              \
      union { unsigned int w[4]; bf16x8 v; } ua, ub;                           \
      ua.w[0] = hi ? X0 : A0; ua.w[1] = hi ? X1 : A1;                          \
      ua.w[2] = hi ? B0 : X0; ua.w[3] = hi ? B1 : X1;                          \
      ub.w[0] = hi ? Y0 : C0; ub.w[1] = hi ? Y1 : C1;                          \
      ub.w[2] = hi ? D0 : Y0; ub.w[3] = hi ? D1 : Y1;                          \
      fa = ua.v; fb = ub.v;                                                    \
    }

    SOFTMAX(sA, kv0)
    PACK2(pa0, pa1)
    if (doUp) {
      SOFTMAX(sB, kv0 + 32)
      PACK2(pa2, pa3)
    }

    __builtin_amdgcn_s_setprio(1);
    accl = mfma32(pa0, onesf, accl);
    accl = mfma32(pa1, onesf, accl);
    if (doUp) {
      accl = mfma32(pa2, onesf, accl);
      accl = mfma32(pa3, onesf, accl);
    }
#pragma unroll
    for (int dt = 0; dt < 4; ++dt) {
      const int vrow = dt * 16 + (ln >> 1);
      const int gb   = (ln & 1) << 3;
      {
        const int sl = (gb + 0 + hi) ^ (vrow & 15);
        const bf16x8 vf = *(const bf16x8*)(vsb + vrow * 256 + sl * 16);
        acc[dt] = mfma32(pa0, vf, acc[dt]);
      }
      {
        const int sl = (gb + 2 + hi) ^ (vrow & 15);
        const bf16x8 vf = *(const bf16x8*)(vsb + vrow * 256 + sl * 16);
        acc[dt] = mfma32(pa1, vf, acc[dt]);
      }
      if (doUp) {
        {
          const int sl = (gb + 4 + hi) ^ (vrow & 15);
          const bf16x8 vf = *(const bf16x8*)(vsb + vrow * 256 + sl * 16);
          acc[dt] = mfma32(pa2, vf, acc[dt]);
        }
        {
          const int sl = (gb + 6 + hi) ^ (vrow & 15);
          const bf16x8 vf = *(const bf16x8*)(vsb + vrow * 256 + sl * 16);
          acc[dt] = mfma32(pa3, vf, acc[dt]);
        }
      }
    }
    __builtin_amdgcn_s_setprio(0);
#undef SOFTMAX
#undef PACK2
  }

  if (chunk < 0) {
    unsigned short* ob = Ob + (size_t)(b * S_LEN + qw) * HID_ + h * D_ + ln;
#pragma unroll
    for (int rr = 0; rr < 16; ++rr) {
      const int qr = (rr & 3) + 8 * (rr >> 2) + 4 * hi;
      const float inv = 1.0f / accl[rr];
#pragma unroll
      for (int dt = 0; dt < 4; ++dt)
        ob[(size_t)qr * HID_ + dt * 32] = f2b(acc[dt][rr] * inv);
    }
  } else {
    const int slot = ((chunk * 2 + b) * 16 + h) * 32 + (qt - 32);
    unsigned short* pa = Pacc + (size_t)slot * 32 * 128 + ln;
#pragma unroll
    for (int rr = 0; rr < 16; ++rr) {
      const int qr = (rr & 3) + 8 * (rr >> 2) + 4 * hi;
#pragma unroll
      for (int dt = 0; dt < 4; ++dt)
        pa[qr * 128 + dt * 32] = f2b(acc[dt][rr]);
    }
    if (ln == 0) {
#pragma unroll
      for (int rr = 0; rr < 16; ++rr) {
        const int qr = (rr & 3) + 8 * (rr >> 2) + 4 * hi;
        Pl[slot * 32 + qr] = accl[rr];
      }
    }
  }
#undef STAGE
}

// combine: out = (A0 + A1) / (L0 + L1) for all split (b,h,qt>=32)
__global__ __launch_bounds__(256)
void combine_k(const unsigned short* __restrict__ Pacc,
               const float* __restrict__ Pl,
               unsigned short* __restrict__ Ob) {
  const int x  = blockIdx.x;           // 1024 = b(2) x h(16) x qs(32)
  const int qs = x & 31;
  const int h  = (x >> 5) & 15;
  const int b  = x >> 9;
  const int tid = threadIdx.x;
  const int q  = tid >> 3;             // 0..31
  const int dp = (tid & 7) * 16;       // 0..112
  const int s0 = (b * 16 + h) * 32 + qs;
  const int s1 = ((2 + b) * 16 + h) * 32 + qs;
  const float inv = 1.0f / (Pl[s0 * 32 + q] + Pl[s1 * 32 + q]);
  const unsigned short* a0 = Pacc + ((size_t)s0 * 32 + q) * 128 + dp;
  const unsigned short* a1 = Pacc + ((size_t)s1 * 32 + q) * 128 + dp;
  unsigned short* ob =
      Ob + (size_t)(b * S_LEN + (32 + qs) * 32 + q) * HID_ + h * D_ + dp;
  const bf16x8 v0a = *(const bf16x8*)a0, v0b = *(const bf16x8*)(a0 + 8);
  const bf16x8 v1a = *(const bf16x8*)a1, v1b = *(const bf16x8*)(a1 + 8);
  bf16x8 oa, obv;
#pragma unroll
  for (int e = 0; e < 8; ++e) {
    oa[e]  = (short)f2b((b2f((unsigned short)v0a[e]) + b2f((unsigned short)v1a[e])) * inv);
    obv[e] = (short)f2b((b2f((unsigned short)v0b[e]) + b2f((unsigned short)v1b[e])) * inv);
  }
  *(bf16x8*)ob = oa;
  *(bf16x8*)(ob + 8) = obv;
}

// ---------------- launcher ----------------

extern "C" void kernel_launch(void* const* d_in, const int* in_sizes, int n_in,
                              void* d_out, int out_size, void* d_ws, size_t ws_size,
                              hipStream_t stream) {
  (void)in_sizes; (void)n_in; (void)out_size; (void)ws_size;
  const float* x  = (const float*)d_in[0];
  const float* Wq = (const float*)d_in[2];
  const float* bq = (const float*)d_in[3];
  const float* Wk = (const float*)d_in[4];
  const float* bk = (const float*)d_in[5];
  const float* Wv = (const float*)d_in[6];
  const float* bv = (const float*)d_in[7];
  const float* Wo = (const float*)d_in[8];
  const float* bo = (const float*)d_in[9];
  float* out = (float*)d_out;

  char* p = (char*)d_ws;
  unsigned short* xb   = (unsigned short*)p;  p += (size_t)4096 * 2048 * 2;
  unsigned short* Wcat = (unsigned short*)p;  p += (size_t)2304 * 2048 * 2;
  float*          bcat = (float*)p;           p += 16384;
  unsigned short* Wob  = (unsigned short*)p;  p += (size_t)2048 * 2048 * 2;
  unsigned short* QKV  = (unsigned short*)p;  p += (size_t)4096 * 2304 * 2;
  unsigned short* Vt   = (unsigned short*)p;  p += (size_t)2 * 128 * 2048 * 2;
  float*          Kmax = (float*)p;           p += 64;
  unsigned short* Pacc = (unsigned short*)p;  p += (size_t)2048 * 32 * 128 * 2; // 16.8MB
  float*          Pl   = (float*)p;           p += (size_t)2048 * 32 * 4;       // 256KB
  unsigned short* Ob   = xb;  // xb dead after gemm1

  prep_k<<<16896, 256, 0, stream>>>(x, xb, Wo, Wob, Wq, Wk, Wv, bq, bk, bv,
                                    Wcat, bcat, Kmax);
  gemm4<0, 3><<<768, 256, 0, stream>>>(xb, Wcat, bcat, QKV, 2304, 2048);
  tvkm_k<<<dim3(32, 2), 256, 0, stream>>>(QKV, Vt, Kmax);
  mqa_attn<<<768, 256, 0, stream>>>(QKV, Vt, Kmax, Ob, Pacc, Pl);
  combine_k<<<1024, 256, 0, stream>>>(Pacc, Pl, Ob);
  gemm4<1, 4><<<512, 256, 0, stream>>>(Ob, Wob, bo, out, 2048, 2048);
}